// Round 7
// baseline (250.999 us; speedup 1.0000x reference)
//
#include <hip/hip_runtime.h>

// 2-layer GCN: h1 = emb[x] @ W1; agg+b1+relu; @ W2; agg+b2.
// CSR built per-launch via two-level binned counting sort (no global atomics).
// R7: layer-1 aggregation split into two 16-channel passes so the gather
// footprint (3.2MB fp16) fits a 4MB per-XCD L2 (R6: 6.4MB footprint gave
// ~50% miss to L3/HBM, latency-bound at 1.18 TB/s). binsort stages its
// bin's pairs in LDS (kills the 12.8MB global re-read).

#define BS   256
#define NBLK 256          // blocks for hist/binscatter passes (MUST stay 256)
#define BINSHIFT 7        // 128 nodes per bin
#define BIN  128
#define MAXBINS 1024
#define BINCAP 3072       // LDS staging capacity (mean bin = 2047, sigma ~45)

// ---- pass A: per-block histograms of dst bins -------------------------------
__global__ void k_hist(const int* __restrict__ dst, int E, int NBINS,
                       int* __restrict__ histG) {
    __shared__ int h[MAXBINS];
    int t = threadIdx.x;
    for (int i = t; i < NBINS; i += BS) h[i] = 0;
    __syncthreads();
    int chunk = (E + NBLK - 1) / NBLK;
    int s = blockIdx.x * chunk;
    int eend = s + chunk; if (eend > E) eend = E;
    for (int e = s + t; e < eend; e += BS) atomicAdd(&h[dst[e] >> BINSHIFT], 1);
    __syncthreads();
    for (int i = t; i < NBINS; i += BS) histG[i * NBLK + blockIdx.x] = h[i];
}

// ---- hierarchical exclusive scan over L = NBINS*NBLK ints -------------------
__global__ void k_scanA(const int* __restrict__ in, int L,
                        int* __restrict__ partial, int* __restrict__ bsum) {
    __shared__ int s[BS];
    int t = threadIdx.x;
    int i = blockIdx.x * BS + t;
    int v = (i < L) ? in[i] : 0;
    s[t] = v;
    __syncthreads();
    for (int off = 1; off < BS; off <<= 1) {
        int add = (t >= off) ? s[t - off] : 0;
        __syncthreads();
        s[t] += add;
        __syncthreads();
    }
    if (i < L) partial[i] = s[t] - v;
    if (t == BS - 1) bsum[blockIdx.x] = s[BS - 1];
}

__global__ void k_scanB(const int* __restrict__ bsum, int nB, int* __restrict__ boff) {
    __shared__ int s[BS];
    int t = threadIdx.x;
    int PER = (nB + BS - 1) / BS;
    int loc[8];
    int base = t * PER;
    int sum = 0;
    for (int j = 0; j < PER && j < 8; j++) {
        int idx = base + j;
        int v = (idx < nB) ? bsum[idx] : 0;
        loc[j] = sum;
        sum += v;
    }
    s[t] = sum;
    __syncthreads();
    for (int off = 1; off < BS; off <<= 1) {
        int add = (t >= off) ? s[t - off] : 0;
        __syncthreads();
        s[t] += add;
        __syncthreads();
    }
    int ex = s[t] - sum;
    for (int j = 0; j < PER && j < 8; j++) {
        int idx = base + j;
        if (idx < nB) boff[idx] = ex + loc[j];
    }
}

// ---- pass C: scatter edges into bin-partitioned order (LDS cursors only) ----
__global__ void k_binscatter(const int* __restrict__ src, const int* __restrict__ dst,
                             int E, int NBINS, const int* __restrict__ partial,
                             const int* __restrict__ boff, int2* __restrict__ pairs) {
    __shared__ int cur[MAXBINS];
    int t = threadIdx.x;
    for (int i = t; i < NBINS; i += BS)
        cur[i] = partial[i * NBLK + blockIdx.x] + boff[i];
    __syncthreads();
    int chunk = (E + NBLK - 1) / NBLK;
    int s = blockIdx.x * chunk;
    int eend = s + chunk; if (eend > E) eend = E;
    for (int e = s + t; e < eend; e += BS) {
        int d = dst[e];
        int pos = atomicAdd(&cur[d >> BINSHIFT], 1);     // LDS atomic
        pairs[pos] = make_int2(src[e], d);
    }
}

// ---- pass D: per-bin counting sort (pairs staged in LDS) --------------------
__global__ void k_binsort(const int2* __restrict__ pairs, const int* __restrict__ partial,
                          const int* __restrict__ boff, int NBINS, int N, int E,
                          int* __restrict__ row_start, float* __restrict__ dinv,
                          int* __restrict__ col) {
    __shared__ int2 buf[BINCAP];                 // 24 KB staging
    __shared__ int ldeg[BIN];
    __shared__ int lrs[BIN];
    __shared__ int cur[BIN];
    int b = blockIdx.x;
    int t = threadIdx.x;
    int node0 = b << BINSHIFT;
    int e0 = partial[b * NBLK] + boff[b];
    int e1 = (b + 1 < NBINS) ? (partial[(b + 1) * NBLK] + boff[b + 1]) : E;
    int cnt = e1 - e0;
    bool fits = (cnt <= BINCAP);                 // uniform per block
    if (b == 0 && t == 0) row_start[N] = E;      // sentinel
    if (t < BIN) ldeg[t] = 0;
    if (fits)
        for (int i = t; i < cnt; i += BS) buf[i] = pairs[e0 + i];
    __syncthreads();
    for (int i = t; i < cnt; i += BS) {
        int2 p = fits ? buf[i] : pairs[e0 + i];
        atomicAdd(&ldeg[p.y - node0], 1);
    }
    __syncthreads();
    if (t < BIN) lrs[t] = ldeg[t];
    __syncthreads();
    for (int off = 1; off < BIN; off <<= 1) {
        int add = (t < BIN && t >= off) ? lrs[t - off] : 0;
        __syncthreads();
        if (t < BIN) lrs[t] += add;
        __syncthreads();
    }
    if (t < BIN) {
        int ex = lrs[t] - ldeg[t];
        cur[t] = ex;
        int n = node0 + t;
        if (n < N) {
            row_start[n] = e0 + ex;
            dinv[n] = rsqrtf((float)(ldeg[t] + 1));
        }
    }
    __syncthreads();
    for (int i = t; i < cnt; i += BS) {
        int2 p = fits ? buf[i] : pairs[e0 + i];
        int pos = atomicAdd(&cur[p.y - node0], 1);       // LDS atomic
        col[e0 + pos] = p.x;
    }
}

// ---- sig1{a,b}[n][c] = dinv[n] * (emb[x[n]] @ W1)[c]  (fp16, split halves) --
__global__ void k_mm1(const int* __restrict__ x, const float* __restrict__ emb,
                      const float* __restrict__ W1, const float* __restrict__ dinv,
                      int N, _Float16* __restrict__ sig1a, _Float16* __restrict__ sig1b) {
    __shared__ float sW[16 * 32];
    __shared__ float sE[8][17];
    int t = threadIdx.x;
    sW[t] = W1[t];
    sW[t + 256] = W1[t + 256];
    int n0 = blockIdx.x * 8;
    if (t < 128) {
        int nl = t >> 4, k = t & 15;
        int n = n0 + nl;
        sE[nl][k] = (n < N) ? emb[x[n] * 16 + k] : 0.f;
    }
    __syncthreads();
    int nl = t >> 5, c = t & 31;
    int n = n0 + nl;
    if (n < N) {
        float acc = 0.f;
        #pragma unroll
        for (int k = 0; k < 16; k++) acc += sE[nl][k] * sW[k * 32 + c];
        float v = acc * dinv[n];
        if (c < 16) sig1a[n * 16 + c] = (_Float16)v;
        else        sig1b[n * 16 + (c - 16)] = (_Float16)v;
    }
}

// ---- generic 16-channel gather-reduce pass (no epilogue) --------------------
// one WAVE per node; lanes = (edge-group e4 in [0,4)) x (channel c in [0,16)).
// 3.2MB footprint -> per-XCD-L2 resident. acc written nontemporal (keep L2 hot).
__global__ __launch_bounds__(BS) void k_aggh(
    const _Float16* __restrict__ sigh, const int* __restrict__ row_start,
    const int* __restrict__ col, int N, float* __restrict__ acch) {
    int t = threadIdx.x;
    int lane = t & 63;
    int n = blockIdx.x * (BS / 64) + (t >> 6);
    if (n >= N) return;
    int e4 = lane >> 4;
    int c  = lane & 15;
    int rs = __builtin_amdgcn_readfirstlane(row_start[n]);
    int re = __builtin_amdgcn_readfirstlane(row_start[n + 1]);
    int dn = re - rs;
    float acc = 0.f;
    int e = 0;
    for (; e + 16 <= dn; e += 16) {
        const int* cu = col + rs + e;            // uniform -> s_load
        int sA0 = (e4 & 1) ? cu[1]  : cu[0];
        int sB0 = (e4 & 1) ? cu[3]  : cu[2];
        int s0  = (e4 & 2) ? sB0 : sA0;
        int sA1 = (e4 & 1) ? cu[5]  : cu[4];
        int sB1 = (e4 & 1) ? cu[7]  : cu[6];
        int s1  = (e4 & 2) ? sB1 : sA1;
        int sA2 = (e4 & 1) ? cu[9]  : cu[8];
        int sB2 = (e4 & 1) ? cu[11] : cu[10];
        int s2  = (e4 & 2) ? sB2 : sA2;
        int sA3 = (e4 & 1) ? cu[13] : cu[12];
        int sB3 = (e4 & 1) ? cu[15] : cu[14];
        int s3  = (e4 & 2) ? sB3 : sA3;
        float v0 = (float)sigh[s0 * 16 + c];
        float v1 = (float)sigh[s1 * 16 + c];
        float v2 = (float)sigh[s2 * 16 + c];
        float v3 = (float)sigh[s3 * 16 + c];
        acc += (v0 + v1) + (v2 + v3);
    }
    if (e + 8 <= dn) {
        const int* cu = col + rs + e;
        int sA0 = (e4 & 1) ? cu[1] : cu[0];
        int sB0 = (e4 & 1) ? cu[3] : cu[2];
        int s0  = (e4 & 2) ? sB0 : sA0;
        int sA1 = (e4 & 1) ? cu[5] : cu[4];
        int sB1 = (e4 & 1) ? cu[7] : cu[6];
        int s1  = (e4 & 2) ? sB1 : sA1;
        acc += (float)sigh[s0 * 16 + c] + (float)sigh[s1 * 16 + c];
        e += 8;
    }
    if (e + 4 <= dn) {
        const int* cu = col + rs + e;
        int sA = (e4 & 1) ? cu[1] : cu[0];
        int sB = (e4 & 1) ? cu[3] : cu[2];
        int s0 = (e4 & 2) ? sB : sA;
        acc += (float)sigh[s0 * 16 + c];
        e += 4;
    }
    {
        int rem = dn - e;
        if (e4 < rem) {
            int s0 = col[rs + e + e4];
            acc += (float)sigh[s0 * 16 + c];
        }
    }
    acc += __shfl_xor(acc, 16);
    acc += __shfl_xor(acc, 32);
    if (lane < 16) __builtin_nontemporal_store(acc, &acch[n * 16 + c]);
}

// ---- epilogue: combine halves + self-loop + norm + b1 + relu + W2 -> sig2 ---
__global__ void k_epi1(const float* __restrict__ acc0, const float* __restrict__ acc1,
                       const _Float16* __restrict__ sig1a, const _Float16* __restrict__ sig1b,
                       const float* __restrict__ dinv, const float* __restrict__ b1,
                       const float* __restrict__ W2, int N, _Float16* __restrict__ sig2) {
    __shared__ float sW[32 * 16];
    __shared__ float sH[8][33];
    int t = threadIdx.x;
    sW[t] = W2[t];
    sW[t + 256] = W2[t + 256];
    int nl = t >> 5, c = t & 31;
    int n = blockIdx.x * 8 + nl;
    float h = 0.f;
    if (n < N) {
        int half = c >> 4, cc = c & 15;
        float a = half ? __builtin_nontemporal_load(&acc1[n * 16 + cc])
                       : __builtin_nontemporal_load(&acc0[n * 16 + cc]);
        float self = half ? (float)sig1b[n * 16 + cc] : (float)sig1a[n * 16 + cc];
        h = fmaxf((a + self) * dinv[n] + b1[c], 0.f);
    }
    sH[nl][c] = h;
    __syncthreads();
    if (t < 128) {
        int nl2 = t >> 4, co = t & 15;
        int n2 = blockIdx.x * 8 + nl2;
        if (n2 < N) {
            float a = 0.f;
            #pragma unroll
            for (int k = 0; k < 32; k++) a += sH[nl2][k] * sW[k * 16 + co];
            sig2[n2 * 16 + co] = (_Float16)(a * dinv[n2]);  // pre-scale
        }
    }
}

// ---- layer-2 aggregate + b2 -> out ------------------------------------------
__global__ __launch_bounds__(BS) void k_agg2(
    const _Float16* __restrict__ sig2, const int* __restrict__ row_start,
    const float* __restrict__ dinv, const int* __restrict__ col,
    const float* __restrict__ b2, int N, float* __restrict__ out) {
    int t = threadIdx.x;
    int lane = t & 63;
    int n = blockIdx.x * (BS / 64) + (t >> 6);
    if (n >= N) return;
    int e4 = lane >> 4;
    int c  = lane & 15;
    int rs = __builtin_amdgcn_readfirstlane(row_start[n]);
    int re = __builtin_amdgcn_readfirstlane(row_start[n + 1]);
    int dn = re - rs;
    float acc = 0.f;
    int e = 0;
    for (; e + 16 <= dn; e += 16) {
        const int* cu = col + rs + e;
        int sA0 = (e4 & 1) ? cu[1]  : cu[0];
        int sB0 = (e4 & 1) ? cu[3]  : cu[2];
        int s0  = (e4 & 2) ? sB0 : sA0;
        int sA1 = (e4 & 1) ? cu[5]  : cu[4];
        int sB1 = (e4 & 1) ? cu[7]  : cu[6];
        int s1  = (e4 & 2) ? sB1 : sA1;
        int sA2 = (e4 & 1) ? cu[9]  : cu[8];
        int sB2 = (e4 & 1) ? cu[11] : cu[10];
        int s2  = (e4 & 2) ? sB2 : sA2;
        int sA3 = (e4 & 1) ? cu[13] : cu[12];
        int sB3 = (e4 & 1) ? cu[15] : cu[14];
        int s3  = (e4 & 2) ? sB3 : sA3;
        float v0 = (float)sig2[s0 * 16 + c];
        float v1 = (float)sig2[s1 * 16 + c];
        float v2 = (float)sig2[s2 * 16 + c];
        float v3 = (float)sig2[s3 * 16 + c];
        acc += (v0 + v1) + (v2 + v3);
    }
    if (e + 8 <= dn) {
        const int* cu = col + rs + e;
        int sA0 = (e4 & 1) ? cu[1] : cu[0];
        int sB0 = (e4 & 1) ? cu[3] : cu[2];
        int s0  = (e4 & 2) ? sB0 : sA0;
        int sA1 = (e4 & 1) ? cu[5] : cu[4];
        int sB1 = (e4 & 1) ? cu[7] : cu[6];
        int s1  = (e4 & 2) ? sB1 : sA1;
        acc += (float)sig2[s0 * 16 + c] + (float)sig2[s1 * 16 + c];
        e += 8;
    }
    if (e + 4 <= dn) {
        const int* cu = col + rs + e;
        int sA = (e4 & 1) ? cu[1] : cu[0];
        int sB = (e4 & 1) ? cu[3] : cu[2];
        int s0 = (e4 & 2) ? sB : sA;
        acc += (float)sig2[s0 * 16 + c];
        e += 4;
    }
    {
        int rem = dn - e;
        if (e4 < rem) {
            int s0 = col[rs + e + e4];
            acc += (float)sig2[s0 * 16 + c];
        }
    }
    acc += __shfl_xor(acc, 16);
    acc += __shfl_xor(acc, 32);
    acc += (float)sig2[n * 16 + c];  // self-loop
    if (lane < 16) out[n * 16 + c] = acc * dinv[n] + b2[c];
}

extern "C" void kernel_launch(void* const* d_in, const int* in_sizes, int n_in,
                              void* d_out, int out_size, void* d_ws, size_t ws_size,
                              hipStream_t stream) {
    const int*   x   = (const int*)d_in[0];
    const int*   ei  = (const int*)d_in[1];
    const float* emb = (const float*)d_in[2];
    const float* W1  = (const float*)d_in[3];
    const float* b1  = (const float*)d_in[4];
    const float* W2  = (const float*)d_in[5];
    const float* b2  = (const float*)d_in[6];
    float* out = (float*)d_out;

    const int N = in_sizes[0];
    const int E = in_sizes[1] / 2;
    const int* srcp = ei;
    const int* dstp = ei + E;
    const int NBINS = (N + BIN - 1) >> BINSHIFT;   // 782 for N=100000
    const int L = NBINS * NBLK;
    const int nB2 = (L + BS - 1) / BS;

    auto al = [](size_t b) { return (b + 255) & ~size_t(255); };
    char* w = (char*)d_ws;
    auto carve = [&](size_t bytes) {
        void* p = (void*)w;
        w += al(bytes);
        return p;
    };
    int*   row_start = (int*)carve((size_t)(N + 1) * 4);
    float* dinv      = (float*)carve((size_t)N * 4);
    int*   col       = (int*)carve((size_t)E * 4);
    // union: CSR-build scratch (histG/partial/bsum/boff/pairs) vs
    //        post-build feature arrays (sig1a/sig1b/sig2/acc0/acc1)
    size_t buildB = al((size_t)L * 4) + al((size_t)L * 4) + al((size_t)nB2 * 4)
                  + al((size_t)nB2 * 4) + al((size_t)E * 8);
    size_t hN16_2 = al((size_t)N * 16 * 2);
    size_t hN16_4 = al((size_t)N * 16 * 4);
    size_t postB  = 3 * hN16_2 + 2 * hN16_4;
    char*  uni    = (char*)carve(buildB > postB ? buildB : postB);
    // build-phase pointers
    char* p = uni;
    int* histG   = (int*)p;  p += al((size_t)L * 4);
    int* partial = (int*)p;  p += al((size_t)L * 4);
    int* bsum    = (int*)p;  p += al((size_t)nB2 * 4);
    int* boff    = (int*)p;  p += al((size_t)nB2 * 4);
    int2* pairs  = (int2*)p;
    // post-phase pointers (overlap is safe: first use is after k_binsort)
    p = uni;
    _Float16* sig1a = (_Float16*)p; p += hN16_2;
    _Float16* sig1b = (_Float16*)p; p += hN16_2;
    _Float16* sig2  = (_Float16*)p; p += hN16_2;
    float*    acc0  = (float*)p;    p += hN16_4;
    float*    acc1  = (float*)p;
    (void)ws_size; (void)n_in; (void)out_size;

    int gL = (L + BS - 1) / BS;
    k_hist<<<NBLK, BS, 0, stream>>>(dstp, E, NBINS, histG);
    k_scanA<<<gL, BS, 0, stream>>>(histG, L, partial, bsum);
    k_scanB<<<1, BS, 0, stream>>>(bsum, nB2, boff);
    k_binscatter<<<NBLK, BS, 0, stream>>>(srcp, dstp, E, NBINS, partial, boff, pairs);
    k_binsort<<<NBINS, BS, 0, stream>>>(pairs, partial, boff, NBINS, N, E,
                                        row_start, dinv, col);

    int g8 = (N + 7) / 8;
    int gW = (N * 64 + BS - 1) / BS;   // one wave (64 lanes) per node
    k_mm1<<<g8, BS, 0, stream>>>(x, emb, W1, dinv, N, sig1a, sig1b);
    k_aggh<<<gW, BS, 0, stream>>>(sig1a, row_start, col, N, acc0);
    k_aggh<<<gW, BS, 0, stream>>>(sig1b, row_start, col, N, acc1);
    k_epi1<<<g8, BS, 0, stream>>>(acc0, acc1, sig1a, sig1b, dinv, b1, W2, N, sig2);
    k_agg2<<<gW, BS, 0, stream>>>(sig2, row_start, dinv, col, b2, N, out);
}

// Round 8
// 227.034 us; speedup vs baseline: 1.1056x; 1.1056x over previous
//
#include <hip/hip_runtime.h>

// 2-layer GCN: h1 = emb[x] @ W1; agg+b1+relu; @ W2; agg+b2.
// CSR built per-launch via two-level binned counting sort (no global atomics).
// R8 (reverts R7's channel split): node-per-wave gather with dword-packed
// fp16 rows; one coalesced col load per 16/32 edges distributed via shfl;
// 16 (agg1) / 32 (agg2) rows in flight per wave. Build uses srcbuf+dstl
// (5B/edge) instead of int2 pairs (8B) and stages dst keys in LDS.

#define BS   256
#define NBLK 256          // blocks for hist/binscatter passes (MUST stay 256)
#define BINSHIFT 7        // 128 nodes per bin
#define BIN  128
#define MAXBINS 1024
#define BINCAP 3072       // LDS dstl staging capacity (mean bin = 2047)

union H2 { int i; _Float16 h[2]; };

// ---- pass A: per-block histograms of dst bins -------------------------------
__global__ void k_hist(const int* __restrict__ dst, int E, int NBINS,
                       int* __restrict__ histG) {
    __shared__ int h[MAXBINS];
    int t = threadIdx.x;
    for (int i = t; i < NBINS; i += BS) h[i] = 0;
    __syncthreads();
    int chunk = (E + NBLK - 1) / NBLK;
    int s = blockIdx.x * chunk;
    int eend = s + chunk; if (eend > E) eend = E;
    for (int e = s + t; e < eend; e += BS) atomicAdd(&h[dst[e] >> BINSHIFT], 1);
    __syncthreads();
    for (int i = t; i < NBINS; i += BS) histG[i * NBLK + blockIdx.x] = h[i];
}

// ---- hierarchical exclusive scan over L = NBINS*NBLK ints -------------------
__global__ void k_scanA(const int* __restrict__ in, int L,
                        int* __restrict__ partial, int* __restrict__ bsum) {
    __shared__ int s[BS];
    int t = threadIdx.x;
    int i = blockIdx.x * BS + t;
    int v = (i < L) ? in[i] : 0;
    s[t] = v;
    __syncthreads();
    for (int off = 1; off < BS; off <<= 1) {
        int add = (t >= off) ? s[t - off] : 0;
        __syncthreads();
        s[t] += add;
        __syncthreads();
    }
    if (i < L) partial[i] = s[t] - v;
    if (t == BS - 1) bsum[blockIdx.x] = s[BS - 1];
}

__global__ void k_scanB(const int* __restrict__ bsum, int nB, int* __restrict__ boff) {
    __shared__ int s[BS];
    int t = threadIdx.x;
    int PER = (nB + BS - 1) / BS;
    int loc[8];
    int base = t * PER;
    int sum = 0;
    for (int j = 0; j < PER && j < 8; j++) {
        int idx = base + j;
        int v = (idx < nB) ? bsum[idx] : 0;
        loc[j] = sum;
        sum += v;
    }
    s[t] = sum;
    __syncthreads();
    for (int off = 1; off < BS; off <<= 1) {
        int add = (t >= off) ? s[t - off] : 0;
        __syncthreads();
        s[t] += add;
        __syncthreads();
    }
    int ex = s[t] - sum;
    for (int j = 0; j < PER && j < 8; j++) {
        int idx = base + j;
        if (idx < nB) boff[idx] = ex + loc[j];
    }
}

// ---- pass C: scatter edges into bin-partitioned order (LDS cursors only) ----
// writes src (4B) + local-dst key (1B) instead of int2 pairs (8B).
__global__ void k_binscatter(const int* __restrict__ src, const int* __restrict__ dst,
                             int E, int NBINS, const int* __restrict__ partial,
                             const int* __restrict__ boff,
                             int* __restrict__ srcbuf, unsigned char* __restrict__ dstl) {
    __shared__ int cur[MAXBINS];
    int t = threadIdx.x;
    for (int i = t; i < NBINS; i += BS)
        cur[i] = partial[i * NBLK + blockIdx.x] + boff[i];
    __syncthreads();
    int chunk = (E + NBLK - 1) / NBLK;
    int s = blockIdx.x * chunk;
    int eend = s + chunk; if (eend > E) eend = E;
    for (int e = s + t; e < eend; e += BS) {
        int d = dst[e];
        int pos = atomicAdd(&cur[d >> BINSHIFT], 1);     // LDS atomic
        srcbuf[pos] = src[e];
        dstl[pos] = (unsigned char)(d & (BIN - 1));
    }
}

// ---- pass D: per-bin counting sort (dst keys staged in LDS) -----------------
__global__ void k_binsort(const int* __restrict__ srcbuf,
                          const unsigned char* __restrict__ dstl,
                          const int* __restrict__ partial, const int* __restrict__ boff,
                          int NBINS, int N, int E,
                          int* __restrict__ row_start, float* __restrict__ dinv,
                          int* __restrict__ col) {
    __shared__ unsigned char dl[BINCAP];         // 3 KB key staging
    __shared__ int ldeg[BIN];
    __shared__ int lrs[BIN];
    __shared__ int cur[BIN];
    int b = blockIdx.x;
    int t = threadIdx.x;
    int e0 = partial[b * NBLK] + boff[b];
    int e1 = (b + 1 < NBINS) ? (partial[(b + 1) * NBLK] + boff[b + 1]) : E;
    int cnt = e1 - e0;
    bool fits = (cnt <= BINCAP);                 // uniform per block
    if (b == 0 && t == 0) row_start[N] = E;      // sentinel
    if (t < BIN) ldeg[t] = 0;
    if (fits)
        for (int i = t; i < cnt; i += BS) dl[i] = dstl[e0 + i];
    __syncthreads();
    for (int i = t; i < cnt; i += BS)
        atomicAdd(&ldeg[fits ? dl[i] : dstl[e0 + i]], 1);
    __syncthreads();
    if (t < BIN) lrs[t] = ldeg[t];
    __syncthreads();
    for (int off = 1; off < BIN; off <<= 1) {
        int add = (t < BIN && t >= off) ? lrs[t - off] : 0;
        __syncthreads();
        if (t < BIN) lrs[t] += add;
        __syncthreads();
    }
    if (t < BIN) {
        int ex = lrs[t] - ldeg[t];
        cur[t] = ex;
        int n = (b << BINSHIFT) + t;
        if (n < N) {
            row_start[n] = e0 + ex;
            dinv[n] = rsqrtf((float)(ldeg[t] + 1));
        }
    }
    __syncthreads();
    for (int i = t; i < cnt; i += BS) {
        int key = fits ? dl[i] : dstl[e0 + i];
        int p = srcbuf[e0 + i];                  // streaming read (once)
        int pos = atomicAdd(&cur[key], 1);       // LDS atomic
        col[e0 + pos] = p;
    }
}

// ---- sig1[n][c] = dinv[n] * (emb[x[n]] @ W1)[c]  (fp16, pre-scaled) ---------
__global__ void k_mm1(const int* __restrict__ x, const float* __restrict__ emb,
                      const float* __restrict__ W1, const float* __restrict__ dinv,
                      int N, _Float16* __restrict__ sig1) {
    __shared__ float sW[16 * 32];
    __shared__ float sE[8][17];
    int t = threadIdx.x;
    sW[t] = W1[t];
    sW[t + 256] = W1[t + 256];
    int n0 = blockIdx.x * 8;
    if (t < 128) {
        int nl = t >> 4, k = t & 15;
        int n = n0 + nl;
        sE[nl][k] = (n < N) ? emb[x[n] * 16 + k] : 0.f;
    }
    __syncthreads();
    int nl = t >> 5, c = t & 31;
    int n = n0 + nl;
    if (n < N) {
        float acc = 0.f;
        #pragma unroll
        for (int k = 0; k < 16; k++) acc += sE[nl][k] * sW[k * 32 + c];
        sig1[n * 32 + c] = (_Float16)(acc * dinv[n]);
    }
}

// ---- fused layer-1 aggregate + b1 + relu + GEMM W2 -> sig2 (fp16) -----------
// one WAVE per node; lanes = (edge-group g in [0,4)) x (dword-channel cd in
// [0,16), 2 fp16 each). One coalesced col load per 16 edges, shfl-distributed;
// 4 gather insts x 4 full 64B rows = 16 rows in flight per wave.
__global__ __launch_bounds__(BS) void k_agg1mm2(
    const _Float16* __restrict__ sig1, const int* __restrict__ row_start,
    const float* __restrict__ dinv, const int* __restrict__ col,
    const float* __restrict__ b1, const float* __restrict__ W2,
    int N, _Float16* __restrict__ sig2) {
    __shared__ float sW[32][17];                 // +1 pad: epilogue bank spread
    int t = threadIdx.x;
    sW[t >> 4][t & 15] = W2[t];
    sW[(t >> 4) + 16][t & 15] = W2[t + 256];
    __syncthreads();
    int lane = t & 63;
    int n = blockIdx.x * (BS / 64) + (t >> 6);
    if (n >= N) return;
    int g  = lane >> 4;              // edge group 0..3
    int cd = lane & 15;              // dword channel (2 fp16)
    const int* s1i = (const int*)sig1;
    int rs = __builtin_amdgcn_readfirstlane(row_start[n]);
    int re = __builtin_amdgcn_readfirstlane(row_start[n + 1]);
    int dn = re - rs;
    float a0 = 0.f, a1 = 0.f;
    int e = 0;
    for (; e + 16 <= dn; e += 16) {
        int colv = col[rs + e + cd];             // one 64B coalesced load
        int s0 = __shfl(colv, g);
        int s1 = __shfl(colv, 4 + g);
        int s2 = __shfl(colv, 8 + g);
        int s3 = __shfl(colv, 12 + g);
        H2 u0, u1, u2, u3;
        u0.i = s1i[s0 * 16 + cd];                // 4 rows (64B each) per inst
        u1.i = s1i[s1 * 16 + cd];
        u2.i = s1i[s2 * 16 + cd];
        u3.i = s1i[s3 * 16 + cd];
        a0 += ((float)u0.h[0] + (float)u1.h[0]) + ((float)u2.h[0] + (float)u3.h[0]);
        a1 += ((float)u0.h[1] + (float)u1.h[1]) + ((float)u2.h[1] + (float)u3.h[1]);
    }
    if (e + 8 <= dn) {
        int colv = col[rs + e + (lane & 7)];
        int s0 = __shfl(colv, g);
        int s1 = __shfl(colv, 4 + g);
        H2 u0, u1;
        u0.i = s1i[s0 * 16 + cd];
        u1.i = s1i[s1 * 16 + cd];
        a0 += (float)u0.h[0] + (float)u1.h[0];
        a1 += (float)u0.h[1] + (float)u1.h[1];
        e += 8;
    }
    if (e + 4 <= dn) {
        int colv = col[rs + e + (lane & 3)];
        int s0 = __shfl(colv, g);
        H2 u0;
        u0.i = s1i[s0 * 16 + cd];
        a0 += (float)u0.h[0];
        a1 += (float)u0.h[1];
        e += 4;
    }
    if (g < dn - e) {
        int s0 = col[rs + e + g];
        H2 u0;
        u0.i = s1i[s0 * 16 + cd];
        a0 += (float)u0.h[0];
        a1 += (float)u0.h[1];
    }
    a0 += __shfl_xor(a0, 16); a0 += __shfl_xor(a0, 32);
    a1 += __shfl_xor(a1, 16); a1 += __shfl_xor(a1, 32);
    H2 us; us.i = s1i[n * 16 + cd];              // self-loop (pre-scaled)
    a0 += (float)us.h[0];
    a1 += (float)us.h[1];
    float di = dinv[n];
    float2 b = ((const float2*)b1)[cd];
    float h0 = fmaxf(a0 * di + b.x, 0.f);
    float h1 = fmaxf(a1 * di + b.y, 0.f);
    // 4-way split-k in-wave GEMM: group g sums k in [8g, 8g+8)
    float a = 0.f;
    #pragma unroll
    for (int j = 0; j < 4; j++) {
        int cdk = 4 * g + j;
        float hk0 = __shfl(h0, cdk);
        float hk1 = __shfl(h1, cdk);
        a += hk0 * sW[2 * cdk][cd] + hk1 * sW[2 * cdk + 1][cd];
    }
    a += __shfl_xor(a, 16);
    a += __shfl_xor(a, 32);
    if (lane < 16) sig2[n * 16 + cd] = (_Float16)(a * di);   // pre-scale
}

// ---- layer-2 aggregate + b2 -> out ------------------------------------------
// one WAVE per node; lanes = (edge-group g in [0,8)) x (dword cd in [0,8)).
// 32-edge unroll: 4 gather insts x 8 rows (32B) = 32 rows in flight per wave.
__global__ __launch_bounds__(BS) void k_agg2(
    const _Float16* __restrict__ sig2, const int* __restrict__ row_start,
    const float* __restrict__ dinv, const int* __restrict__ col,
    const float* __restrict__ b2, int N, float* __restrict__ out) {
    int t = threadIdx.x;
    int lane = t & 63;
    int n = blockIdx.x * (BS / 64) + (t >> 6);
    if (n >= N) return;
    int g  = lane >> 3;              // edge group 0..7
    int cd = lane & 7;               // dword channel (2 fp16)
    const int* s2i = (const int*)sig2;
    int rs = __builtin_amdgcn_readfirstlane(row_start[n]);
    int re = __builtin_amdgcn_readfirstlane(row_start[n + 1]);
    int dn = re - rs;
    float a0 = 0.f, a1 = 0.f;
    int e = 0;
    for (; e + 32 <= dn; e += 32) {
        int colv = col[rs + e + (lane & 31)];    // one 128B coalesced load
        int s0 = __shfl(colv, g);
        int s1 = __shfl(colv, 8 + g);
        int s2 = __shfl(colv, 16 + g);
        int s3 = __shfl(colv, 24 + g);
        H2 u0, u1, u2, u3;
        u0.i = s2i[s0 * 8 + cd];
        u1.i = s2i[s1 * 8 + cd];
        u2.i = s2i[s2 * 8 + cd];
        u3.i = s2i[s3 * 8 + cd];
        a0 += ((float)u0.h[0] + (float)u1.h[0]) + ((float)u2.h[0] + (float)u3.h[0]);
        a1 += ((float)u0.h[1] + (float)u1.h[1]) + ((float)u2.h[1] + (float)u3.h[1]);
    }
    if (e + 16 <= dn) {
        int colv = col[rs + e + (lane & 15)];
        int s0 = __shfl(colv, g);
        int s1 = __shfl(colv, 8 + g);
        H2 u0, u1;
        u0.i = s2i[s0 * 8 + cd];
        u1.i = s2i[s1 * 8 + cd];
        a0 += (float)u0.h[0] + (float)u1.h[0];
        a1 += (float)u0.h[1] + (float)u1.h[1];
        e += 16;
    }
    if (e + 8 <= dn) {
        int colv = col[rs + e + (lane & 7)];
        int s0 = __shfl(colv, g);
        H2 u0;
        u0.i = s2i[s0 * 8 + cd];
        a0 += (float)u0.h[0];
        a1 += (float)u0.h[1];
        e += 8;
    }
    if (g < dn - e) {
        int s0 = col[rs + e + g];
        H2 u0;
        u0.i = s2i[s0 * 8 + cd];
        a0 += (float)u0.h[0];
        a1 += (float)u0.h[1];
    }
    a0 += __shfl_xor(a0, 8); a0 += __shfl_xor(a0, 16); a0 += __shfl_xor(a0, 32);
    a1 += __shfl_xor(a1, 8); a1 += __shfl_xor(a1, 16); a1 += __shfl_xor(a1, 32);
    H2 us; us.i = s2i[n * 8 + cd];               // self-loop
    a0 += (float)us.h[0];
    a1 += (float)us.h[1];
    if (lane < 8) {
        float di = dinv[n];
        float2 b = ((const float2*)b2)[cd];
        float2 o;
        o.x = a0 * di + b.x;
        o.y = a1 * di + b.y;
        ((float2*)out)[n * 8 + cd] = o;
    }
}

extern "C" void kernel_launch(void* const* d_in, const int* in_sizes, int n_in,
                              void* d_out, int out_size, void* d_ws, size_t ws_size,
                              hipStream_t stream) {
    const int*   x   = (const int*)d_in[0];
    const int*   ei  = (const int*)d_in[1];
    const float* emb = (const float*)d_in[2];
    const float* W1  = (const float*)d_in[3];
    const float* b1  = (const float*)d_in[4];
    const float* W2  = (const float*)d_in[5];
    const float* b2  = (const float*)d_in[6];
    float* out = (float*)d_out;

    const int N = in_sizes[0];
    const int E = in_sizes[1] / 2;
    const int* srcp = ei;
    const int* dstp = ei + E;
    const int NBINS = (N + BIN - 1) >> BINSHIFT;   // 782 for N=100000
    const int L = NBINS * NBLK;
    const int nB2 = (L + BS - 1) / BS;

    auto al = [](size_t b) { return (b + 255) & ~size_t(255); };
    char* w = (char*)d_ws;
    auto carve = [&](size_t bytes) {
        void* p = (void*)w;
        w += al(bytes);
        return p;
    };
    int*   row_start = (int*)carve((size_t)(N + 1) * 4);
    float* dinv      = (float*)carve((size_t)N * 4);
    int*   col       = (int*)carve((size_t)E * 4);
    // union: build scratch (histG/partial/bsum/boff/srcbuf/dstl) vs
    //        post-build features (sig1/sig2); build dead after k_binsort.
    size_t buildB = al((size_t)L * 4) + al((size_t)L * 4) + al((size_t)nB2 * 4)
                  + al((size_t)nB2 * 4) + al((size_t)E * 4) + al((size_t)E);
    size_t postB  = al((size_t)N * 32 * 2) + al((size_t)N * 16 * 2);
    char*  uni    = (char*)carve(buildB > postB ? buildB : postB);
    char* p = uni;
    int* histG   = (int*)p;  p += al((size_t)L * 4);
    int* partial = (int*)p;  p += al((size_t)L * 4);
    int* bsum    = (int*)p;  p += al((size_t)nB2 * 4);
    int* boff    = (int*)p;  p += al((size_t)nB2 * 4);
    int* srcbuf  = (int*)p;  p += al((size_t)E * 4);
    unsigned char* dstl = (unsigned char*)p;
    p = uni;
    _Float16* sig1 = (_Float16*)p; p += al((size_t)N * 32 * 2);
    _Float16* sig2 = (_Float16*)p;
    (void)ws_size; (void)n_in; (void)out_size;

    int gL = (L + BS - 1) / BS;
    k_hist<<<NBLK, BS, 0, stream>>>(dstp, E, NBINS, histG);
    k_scanA<<<gL, BS, 0, stream>>>(histG, L, partial, bsum);
    k_scanB<<<1, BS, 0, stream>>>(bsum, nB2, boff);
    k_binscatter<<<NBLK, BS, 0, stream>>>(srcp, dstp, E, NBINS, partial, boff,
                                          srcbuf, dstl);
    k_binsort<<<NBINS, BS, 0, stream>>>(srcbuf, dstl, partial, boff, NBINS, N, E,
                                        row_start, dinv, col);

    int g8 = (N + 7) / 8;
    int gW = (N + 3) / 4;              // one wave (64 lanes) per node, 4/block
    k_mm1<<<g8, BS, 0, stream>>>(x, emb, W1, dinv, N, sig1);
    k_agg1mm2<<<gW, BS, 0, stream>>>(sig1, row_start, dinv, col, b1, W2, N, sig2);
    k_agg2<<<gW, BS, 0, stream>>>(sig2, row_start, dinv, col, b2, N, out);
}

// Round 9
// 200.746 us; speedup vs baseline: 1.2503x; 1.1309x over previous
//
#include <hip/hip_runtime.h>

// 2-layer GCN: h1 = emb[x] @ W1; agg+b1+relu; @ W2; agg+b2.
// CSR built per-launch via two-level binned counting sort (no global atomics).
// R9: binscatter writes ONE packed int per edge (src | dstLocal<<24 -- R8's
// split srcbuf+dstl gave 81MB of partial-line writes); agg kernels use
// masked single-round edge loops (clamped idx + 0/1 mask) instead of
// geometric tails: per-node dependent memory rounds drop ~5 -> 2.

#define BS   256
#define NBLK 256          // blocks for hist/binscatter passes (MUST stay 256)
#define BINSHIFT 7        // 128 nodes per bin
#define BIN  128
#define MAXBINS 1024
#define BINCAP 3072       // LDS packed staging (mean bin = 2047); 12 KB

union H2 { int i; _Float16 h[2]; };

// ---- pass A: per-block histograms of dst bins -------------------------------
__global__ void k_hist(const int* __restrict__ dst, int E, int NBINS,
                       int* __restrict__ histG) {
    __shared__ int h[MAXBINS];
    int t = threadIdx.x;
    for (int i = t; i < NBINS; i += BS) h[i] = 0;
    __syncthreads();
    int chunk = (E + NBLK - 1) / NBLK;
    int s = blockIdx.x * chunk;
    int eend = s + chunk; if (eend > E) eend = E;
    for (int e = s + t; e < eend; e += BS) atomicAdd(&h[dst[e] >> BINSHIFT], 1);
    __syncthreads();
    for (int i = t; i < NBINS; i += BS) histG[i * NBLK + blockIdx.x] = h[i];
}

// ---- hierarchical exclusive scan over L = NBINS*NBLK ints -------------------
__global__ void k_scanA(const int* __restrict__ in, int L,
                        int* __restrict__ partial, int* __restrict__ bsum) {
    __shared__ int s[BS];
    int t = threadIdx.x;
    int i = blockIdx.x * BS + t;
    int v = (i < L) ? in[i] : 0;
    s[t] = v;
    __syncthreads();
    for (int off = 1; off < BS; off <<= 1) {
        int add = (t >= off) ? s[t - off] : 0;
        __syncthreads();
        s[t] += add;
        __syncthreads();
    }
    if (i < L) partial[i] = s[t] - v;
    if (t == BS - 1) bsum[blockIdx.x] = s[BS - 1];
}

__global__ void k_scanB(const int* __restrict__ bsum, int nB, int* __restrict__ boff) {
    __shared__ int s[BS];
    int t = threadIdx.x;
    int PER = (nB + BS - 1) / BS;
    int loc[8];
    int base = t * PER;
    int sum = 0;
    for (int j = 0; j < PER && j < 8; j++) {
        int idx = base + j;
        int v = (idx < nB) ? bsum[idx] : 0;
        loc[j] = sum;
        sum += v;
    }
    s[t] = sum;
    __syncthreads();
    for (int off = 1; off < BS; off <<= 1) {
        int add = (t >= off) ? s[t - off] : 0;
        __syncthreads();
        s[t] += add;
        __syncthreads();
    }
    int ex = s[t] - sum;
    for (int j = 0; j < PER && j < 8; j++) {
        int idx = base + j;
        if (idx < nB) boff[idx] = ex + loc[j];
    }
}

// ---- pass C: scatter edges into bin-partitioned order (LDS cursors only) ----
// ONE packed 4B write per edge: src | dstLocal<<24  (needs src < 2^24).
__global__ void k_binscatter(const int* __restrict__ src, const int* __restrict__ dst,
                             int E, int NBINS, const int* __restrict__ partial,
                             const int* __restrict__ boff, int* __restrict__ packed) {
    __shared__ int cur[MAXBINS];
    int t = threadIdx.x;
    for (int i = t; i < NBINS; i += BS)
        cur[i] = partial[i * NBLK + blockIdx.x] + boff[i];
    __syncthreads();
    int chunk = (E + NBLK - 1) / NBLK;
    int s = blockIdx.x * chunk;
    int eend = s + chunk; if (eend > E) eend = E;
    for (int e = s + t; e < eend; e += BS) {
        int d = dst[e];
        int pos = atomicAdd(&cur[d >> BINSHIFT], 1);     // LDS atomic
        packed[pos] = src[e] | ((d & (BIN - 1)) << 24);
    }
}

// ---- pass D: per-bin counting sort (packed staged in LDS) -------------------
__global__ void k_binsort(const int* __restrict__ packed,
                          const int* __restrict__ partial, const int* __restrict__ boff,
                          int NBINS, int N, int E,
                          int* __restrict__ row_start, float* __restrict__ dinv,
                          int* __restrict__ col) {
    __shared__ int buf[BINCAP];                  // 12 KB staging
    __shared__ int ldeg[BIN];
    __shared__ int lrs[BIN];
    __shared__ int cur[BIN];
    int b = blockIdx.x;
    int t = threadIdx.x;
    int e0 = partial[b * NBLK] + boff[b];
    int e1 = (b + 1 < NBINS) ? (partial[(b + 1) * NBLK] + boff[b + 1]) : E;
    int cnt = e1 - e0;
    bool fits = (cnt <= BINCAP);                 // uniform per block
    if (b == 0 && t == 0) row_start[N] = E;      // sentinel
    if (t < BIN) ldeg[t] = 0;
    if (fits)
        for (int i = t; i < cnt; i += BS) buf[i] = packed[e0 + i];
    __syncthreads();
    for (int i = t; i < cnt; i += BS) {
        int v = fits ? buf[i] : packed[e0 + i];
        atomicAdd(&ldeg[(unsigned)v >> 24], 1);
    }
    __syncthreads();
    if (t < BIN) lrs[t] = ldeg[t];
    __syncthreads();
    for (int off = 1; off < BIN; off <<= 1) {
        int add = (t < BIN && t >= off) ? lrs[t - off] : 0;
        __syncthreads();
        if (t < BIN) lrs[t] += add;
        __syncthreads();
    }
    if (t < BIN) {
        int ex = lrs[t] - ldeg[t];
        cur[t] = ex;
        int n = (b << BINSHIFT) + t;
        if (n < N) {
            row_start[n] = e0 + ex;
            dinv[n] = rsqrtf((float)(ldeg[t] + 1));
        }
    }
    __syncthreads();
    for (int i = t; i < cnt; i += BS) {
        int v = fits ? buf[i] : packed[e0 + i];
        int pos = atomicAdd(&cur[(unsigned)v >> 24], 1);     // LDS atomic
        col[e0 + pos] = v & 0xFFFFFF;
    }
}

// ---- sig1[n][c] = dinv[n] * (emb[x[n]] @ W1)[c]  (fp16, pre-scaled) ---------
__global__ void k_mm1(const int* __restrict__ x, const float* __restrict__ emb,
                      const float* __restrict__ W1, const float* __restrict__ dinv,
                      int N, _Float16* __restrict__ sig1) {
    __shared__ float sW[16 * 32];
    __shared__ float sE[8][17];
    int t = threadIdx.x;
    sW[t] = W1[t];
    sW[t + 256] = W1[t + 256];
    int n0 = blockIdx.x * 8;
    if (t < 128) {
        int nl = t >> 4, k = t & 15;
        int n = n0 + nl;
        sE[nl][k] = (n < N) ? emb[x[n] * 16 + k] : 0.f;
    }
    __syncthreads();
    int nl = t >> 5, c = t & 31;
    int n = n0 + nl;
    if (n < N) {
        float acc = 0.f;
        #pragma unroll
        for (int k = 0; k < 16; k++) acc += sE[nl][k] * sW[k * 32 + c];
        sig1[n * 32 + c] = (_Float16)(acc * dinv[n]);
    }
}

// ---- fused layer-1 aggregate + b1 + relu + GEMM W2 -> sig2 (fp16) -----------
// one WAVE per node; lanes = (edge-group g in [0,4)) x (dword-channel cd).
// masked single-round loop: ceil(dn/16) iters, clamped idx, 0/1 masks;
// col prefetched one iteration ahead (loads overlap gathers).
__global__ __launch_bounds__(BS) void k_agg1mm2(
    const _Float16* __restrict__ sig1, const int* __restrict__ row_start,
    const float* __restrict__ dinv, const int* __restrict__ col,
    const float* __restrict__ b1, const float* __restrict__ W2,
    int N, _Float16* __restrict__ sig2) {
    __shared__ float sW[32][17];
    int t = threadIdx.x;
    sW[t >> 4][t & 15] = W2[t];
    sW[(t >> 4) + 16][t & 15] = W2[t + 256];
    __syncthreads();
    int lane = t & 63;
    int n = blockIdx.x * (BS / 64) + (t >> 6);
    if (n >= N) return;
    int g  = lane >> 4;              // edge group 0..3
    int cd = lane & 15;              // dword channel (2 fp16)
    const int* s1i = (const int*)sig1;
    int rs = __builtin_amdgcn_readfirstlane(row_start[n]);
    int re = __builtin_amdgcn_readfirstlane(row_start[n + 1]);
    int dn = re - rs;                // wave-uniform
    float a0 = 0.f, a1 = 0.f;
    int iters = (dn + 15) >> 4;
    int colv = 0;
    if (iters > 0) {
        int idx = cd; if (idx > dn - 1) idx = dn - 1;
        colv = col[rs + idx];
    }
    for (int it = 0; it < iters; it++) {
        int e = it << 4;
        int coln = 0;
        if (it + 1 < iters) {
            int idx = e + 16 + cd; if (idx > dn - 1) idx = dn - 1;
            coln = col[rs + idx];                // prefetch next round
        }
        int s0 = __shfl(colv, g);
        int s1 = __shfl(colv, 4 + g);
        int s2 = __shfl(colv, 8 + g);
        int s3 = __shfl(colv, 12 + g);
        H2 u0, u1, u2, u3;
        u0.i = s1i[s0 * 16 + cd];                // 4 rows (64B) in flight
        u1.i = s1i[s1 * 16 + cd];
        u2.i = s1i[s2 * 16 + cd];
        u3.i = s1i[s3 * 16 + cd];
        float m0 = (e + g      < dn) ? 1.f : 0.f;
        float m1 = (e + 4 + g  < dn) ? 1.f : 0.f;
        float m2 = (e + 8 + g  < dn) ? 1.f : 0.f;
        float m3 = (e + 12 + g < dn) ? 1.f : 0.f;
        a0 += (m0 * (float)u0.h[0] + m1 * (float)u1.h[0])
            + (m2 * (float)u2.h[0] + m3 * (float)u3.h[0]);
        a1 += (m0 * (float)u0.h[1] + m1 * (float)u1.h[1])
            + (m2 * (float)u2.h[1] + m3 * (float)u3.h[1]);
        colv = coln;
    }
    a0 += __shfl_xor(a0, 16); a0 += __shfl_xor(a0, 32);
    a1 += __shfl_xor(a1, 16); a1 += __shfl_xor(a1, 32);
    H2 us; us.i = s1i[n * 16 + cd];              // self-loop (pre-scaled)
    a0 += (float)us.h[0];
    a1 += (float)us.h[1];
    float di = dinv[n];
    float2 b = ((const float2*)b1)[cd];
    float h0 = fmaxf(a0 * di + b.x, 0.f);
    float h1 = fmaxf(a1 * di + b.y, 0.f);
    // 4-way split-k in-wave GEMM: group g sums k in [8g, 8g+8)
    float a = 0.f;
    #pragma unroll
    for (int j = 0; j < 4; j++) {
        int cdk = 4 * g + j;
        float hk0 = __shfl(h0, cdk);
        float hk1 = __shfl(h1, cdk);
        a += hk0 * sW[2 * cdk][cd] + hk1 * sW[2 * cdk + 1][cd];
    }
    a += __shfl_xor(a, 16);
    a += __shfl_xor(a, 32);
    if (lane < 16) sig2[n * 16 + cd] = (_Float16)(a * di);   // pre-scale
}

// ---- layer-2 aggregate + b2 -> out ------------------------------------------
// one WAVE per node; lanes = (edge-group g in [0,8)) x (dword cd in [0,8)).
// masked single-round loop: ceil(dn/32) iters; deg<=32 nodes do ONE round.
__global__ __launch_bounds__(BS) void k_agg2(
    const _Float16* __restrict__ sig2, const int* __restrict__ row_start,
    const float* __restrict__ dinv, const int* __restrict__ col,
    const float* __restrict__ b2, int N, float* __restrict__ out) {
    int t = threadIdx.x;
    int lane = t & 63;
    int n = blockIdx.x * (BS / 64) + (t >> 6);
    if (n >= N) return;
    int g  = lane >> 3;              // edge group 0..7
    int cd = lane & 7;               // dword channel (2 fp16)
    const int* s2i = (const int*)sig2;
    int rs = __builtin_amdgcn_readfirstlane(row_start[n]);
    int re = __builtin_amdgcn_readfirstlane(row_start[n + 1]);
    int dn = re - rs;
    float a0 = 0.f, a1 = 0.f;
    int iters = (dn + 31) >> 5;
    int l32 = lane & 31;
    int colv = 0;
    if (iters > 0) {
        int idx = l32; if (idx > dn - 1) idx = dn - 1;
        colv = col[rs + idx];
    }
    for (int it = 0; it < iters; it++) {
        int e = it << 5;
        int coln = 0;
        if (it + 1 < iters) {
            int idx = e + 32 + l32; if (idx > dn - 1) idx = dn - 1;
            coln = col[rs + idx];
        }
        int s0 = __shfl(colv, g);
        int s1 = __shfl(colv, 8 + g);
        int s2 = __shfl(colv, 16 + g);
        int s3 = __shfl(colv, 24 + g);
        H2 u0, u1, u2, u3;
        u0.i = s2i[s0 * 8 + cd];
        u1.i = s2i[s1 * 8 + cd];
        u2.i = s2i[s2 * 8 + cd];
        u3.i = s2i[s3 * 8 + cd];
        float m0 = (e + g      < dn) ? 1.f : 0.f;
        float m1 = (e + 8 + g  < dn) ? 1.f : 0.f;
        float m2 = (e + 16 + g < dn) ? 1.f : 0.f;
        float m3 = (e + 24 + g < dn) ? 1.f : 0.f;
        a0 += (m0 * (float)u0.h[0] + m1 * (float)u1.h[0])
            + (m2 * (float)u2.h[0] + m3 * (float)u3.h[0]);
        a1 += (m0 * (float)u0.h[1] + m1 * (float)u1.h[1])
            + (m2 * (float)u2.h[1] + m3 * (float)u3.h[1]);
        colv = coln;
    }
    a0 += __shfl_xor(a0, 8); a0 += __shfl_xor(a0, 16); a0 += __shfl_xor(a0, 32);
    a1 += __shfl_xor(a1, 8); a1 += __shfl_xor(a1, 16); a1 += __shfl_xor(a1, 32);
    H2 us; us.i = s2i[n * 8 + cd];               // self-loop
    a0 += (float)us.h[0];
    a1 += (float)us.h[1];
    if (lane < 8) {
        float di = dinv[n];
        float2 b = ((const float2*)b2)[cd];
        float2 o;
        o.x = a0 * di + b.x;
        o.y = a1 * di + b.y;
        ((float2*)out)[n * 8 + cd] = o;
    }
}

extern "C" void kernel_launch(void* const* d_in, const int* in_sizes, int n_in,
                              void* d_out, int out_size, void* d_ws, size_t ws_size,
                              hipStream_t stream) {
    const int*   x   = (const int*)d_in[0];
    const int*   ei  = (const int*)d_in[1];
    const float* emb = (const float*)d_in[2];
    const float* W1  = (const float*)d_in[3];
    const float* b1  = (const float*)d_in[4];
    const float* W2  = (const float*)d_in[5];
    const float* b2  = (const float*)d_in[6];
    float* out = (float*)d_out;

    const int N = in_sizes[0];
    const int E = in_sizes[1] / 2;
    const int* srcp = ei;
    const int* dstp = ei + E;
    const int NBINS = (N + BIN - 1) >> BINSHIFT;   // 782 for N=100000
    const int L = NBINS * NBLK;
    const int nB2 = (L + BS - 1) / BS;

    auto al = [](size_t b) { return (b + 255) & ~size_t(255); };
    char* w = (char*)d_ws;
    auto carve = [&](size_t bytes) {
        void* p = (void*)w;
        w += al(bytes);
        return p;
    };
    int*   row_start = (int*)carve((size_t)(N + 1) * 4);
    float* dinv      = (float*)carve((size_t)N * 4);
    int*   col       = (int*)carve((size_t)E * 4);
    // union: build scratch (histG/partial/bsum/boff/packed) vs
    //        post-build features (sig1/sig2); build dead after k_binsort.
    size_t buildB = al((size_t)L * 4) + al((size_t)L * 4) + al((size_t)nB2 * 4)
                  + al((size_t)nB2 * 4) + al((size_t)E * 4);
    size_t postB  = al((size_t)N * 32 * 2) + al((size_t)N * 16 * 2);
    char*  uni    = (char*)carve(buildB > postB ? buildB : postB);
    char* p = uni;
    int* histG   = (int*)p;  p += al((size_t)L * 4);
    int* partial = (int*)p;  p += al((size_t)L * 4);
    int* bsum    = (int*)p;  p += al((size_t)nB2 * 4);
    int* boff    = (int*)p;  p += al((size_t)nB2 * 4);
    int* packed  = (int*)p;
    p = uni;
    _Float16* sig1 = (_Float16*)p; p += al((size_t)N * 32 * 2);
    _Float16* sig2 = (_Float16*)p;
    (void)ws_size; (void)n_in; (void)out_size;

    int gL = (L + BS - 1) / BS;
    k_hist<<<NBLK, BS, 0, stream>>>(dstp, E, NBINS, histG);
    k_scanA<<<gL, BS, 0, stream>>>(histG, L, partial, bsum);
    k_scanB<<<1, BS, 0, stream>>>(bsum, nB2, boff);
    k_binscatter<<<NBLK, BS, 0, stream>>>(srcp, dstp, E, NBINS, partial, boff, packed);
    k_binsort<<<NBINS, BS, 0, stream>>>(packed, partial, boff, NBINS, N, E,
                                        row_start, dinv, col);

    int g8 = (N + 7) / 8;
    int gW = (N + 3) / 4;              // one wave (64 lanes) per node, 4/block
    k_mm1<<<g8, BS, 0, stream>>>(x, emb, W1, dinv, N, sig1);
    k_agg1mm2<<<gW, BS, 0, stream>>>(sig1, row_start, dinv, col, b1, W2, N, sig2);
    k_agg2<<<gW, BS, 0, stream>>>(sig2, row_start, dinv, col, b2, N, out);
}